// Round 1
// baseline (185.107 us; speedup 1.0000x reference)
//
#include <hip/hip_runtime.h>

// Problem: per-batch segment_sum with SORTED segment ids.
//   embeddings: (B=64, S=512, D=768) fp32
//   segment_ids: (B, S) int32, sorted ascending, values in [0, S)
//   out = concat(report_feat (B,D) = agg[:,0],  word_feat (B,S-1,D) = agg[:,1:])
// Sorted ids => segment g's rows form a contiguous run [lb(g), lb(g+1)).
// One thread per output float4: binary search (LDS, wave-uniform) + coalesced
// float4 run-sum + exactly-one write. No atomics, no zero-fill pass.

constexpr int B  = 64;
constexpr int S  = 512;
constexpr int D  = 768;
constexpr int D4 = D / 4;         // 192 float4 per row; 192 % 64 == 0 -> wave-uniform g
constexpr int BLOCK = 256;

__global__ __launch_bounds__(BLOCK) void segsum_kernel(
    const float4* __restrict__ emb,   // (B*S*D4) float4
    const int*    __restrict__ seg,   // (B*S) int
    float4*       __restrict__ out) { // report (B*D4) then word (B*(S-1)*D4)
  __shared__ int srow[S];

  const int flat = blockIdx.x * BLOCK + threadIdx.x;   // < B*S*D4
  const int b    = flat / (S * D4);                    // 98304/256=384 blocks per b -> one b per block

  // Stage this batch row's segment ids into LDS (2 KB).
  const int* row = seg + b * S;
  for (int i = threadIdx.x; i < S; i += BLOCK) srow[i] = row[i];
  __syncthreads();

  const int rem = flat - b * (S * D4);
  const int g   = rem / D4;          // wave-uniform
  const int d4  = rem - g * D4;

  // start = lower_bound(g), end = lower_bound(g+1); all lanes search the same
  // value -> uniform control flow, same-address LDS reads broadcast for free.
  int lo = 0, hi = S;
  while (lo < hi) { int mid = (lo + hi) >> 1; if (srow[mid] < g) lo = mid + 1; else hi = mid; }
  const int start = lo;
  hi = S;                            // lb(g+1) >= lb(g): reuse lo
  while (lo < hi) { int mid = (lo + hi) >> 1; if (srow[mid] < g + 1) lo = mid + 1; else hi = mid; }
  const int end = lo;

  float4 acc = make_float4(0.f, 0.f, 0.f, 0.f);
  const float4* p = emb + (size_t)(b * S + start) * D4 + d4;
  for (int s = start; s < end; ++s) {   // trip count wave-uniform (avg 1.0)
    float4 e = *p; p += D4;
    acc.x += e.x; acc.y += e.y; acc.z += e.z; acc.w += e.w;
  }

  if (g == 0) {
    out[(size_t)b * D4 + d4] = acc;                                        // report_feat
  } else {
    out[(size_t)B * D4 + ((size_t)b * (S - 1) + (g - 1)) * D4 + d4] = acc; // word_feat
  }
}

extern "C" void kernel_launch(void* const* d_in, const int* in_sizes, int n_in,
                              void* d_out, int out_size, void* d_ws, size_t ws_size,
                              hipStream_t stream) {
  const float4* emb = (const float4*)d_in[0];
  const int*    seg = (const int*)d_in[1];
  float4*       out = (float4*)d_out;

  const int total  = B * S * D4;            // 6,291,456 threads
  const int blocks = total / BLOCK;         // 24,576 blocks
  segsum_kernel<<<blocks, BLOCK, 0, stream>>>(emb, seg, out);
}

// Round 2
// 177.336 us; speedup vs baseline: 1.0438x; 1.0438x over previous
//
#include <hip/hip_runtime.h>

// Per-batch segment_sum with SORTED segment ids.
//   embeddings: (B=64, S=512, D=768) fp32; segment_ids: (B,S) int32 sorted.
//   out = concat(agg[:,0] (B,D),  agg[:,1:] (B,S-1,D)) — flat size B*S*D.
//
// R1 post-mortem: per-thread LDS binary search (18 dependent ds_read + ~110
// VALU per thread) made the kernel issue-bound (VALUBusy 44%, HBM 29%).
// R2: two-pass. Pass 1 computes run boundaries once per (b,g) into d_ws
// (131 KB). Pass 2 is pure streaming: 2 uniform L2-hit loads + float4
// run-sum + one coalesced write per thread.

constexpr int B  = 64;
constexpr int S  = 512;
constexpr int D  = 768;
constexpr int D4 = D / 4;          // 192; 192 % 64 == 0 -> g is wave-uniform
constexpr int BLOCK = 256;

// ---------- Pass 1: boundaries[b][g] = lower_bound(seg[b], g); [b][S] = S ----
__global__ __launch_bounds__(256) void boundaries_kernel(
    const int* __restrict__ seg, int* __restrict__ bnd) {
  __shared__ int srow[S];
  const int b = blockIdx.x;
  const int* row = seg + b * S;
  for (int i = threadIdx.x; i < S; i += 256) srow[i] = row[i];
  __syncthreads();
  int* outb = bnd + b * (S + 1);
  for (int g = threadIdx.x; g < S; g += 256) {
    int lo = 0, hi = S;
    while (lo < hi) { int mid = (lo + hi) >> 1; if (srow[mid] < g) lo = mid + 1; else hi = mid; }
    outb[g] = lo;
  }
  if (threadIdx.x == 0) outb[S] = S;
}

// ---------- Pass 2: streaming run-sum ---------------------------------------
__global__ __launch_bounds__(BLOCK) void segsum_kernel2(
    const float4* __restrict__ emb,
    const int*    __restrict__ bnd,
    float4*       __restrict__ out) {
  const int flat = blockIdx.x * BLOCK + threadIdx.x;
  const int b    = flat / (S * D4);
  const int rem  = flat - b * (S * D4);
  const int g    = rem / D4;                 // wave-uniform
  const int d4   = rem - g * D4;

  const int* base  = bnd + b * (S + 1);      // same addr across wave -> broadcast
  const int  start = base[g];
  const int  end   = base[g + 1];

  float4 acc = make_float4(0.f, 0.f, 0.f, 0.f);
  const float4* p = emb + (size_t)(b * S + start) * D4 + d4;
  for (int s = start; s < end; ++s) {        // wave-uniform trip count (avg 1)
    float4 e = *p; p += D4;
    acc.x += e.x; acc.y += e.y; acc.z += e.z; acc.w += e.w;
  }

  if (g == 0) {
    out[(size_t)b * D4 + d4] = acc;                                        // report_feat
  } else {
    out[(size_t)B * D4 + ((size_t)b * (S - 1) + (g - 1)) * D4 + d4] = acc; // word_feat
  }
}

// ---------- Fallback (R1 single-kernel) if d_ws is too small ----------------
__global__ __launch_bounds__(BLOCK) void segsum_kernel1(
    const float4* __restrict__ emb,
    const int*    __restrict__ seg,
    float4*       __restrict__ out) {
  __shared__ int srow[S];
  const int flat = blockIdx.x * BLOCK + threadIdx.x;
  const int b    = flat / (S * D4);
  const int* row = seg + b * S;
  for (int i = threadIdx.x; i < S; i += BLOCK) srow[i] = row[i];
  __syncthreads();
  const int rem = flat - b * (S * D4);
  const int g   = rem / D4;
  const int d4  = rem - g * D4;
  int lo = 0, hi = S;
  while (lo < hi) { int mid = (lo + hi) >> 1; if (srow[mid] < g) lo = mid + 1; else hi = mid; }
  const int start = lo;
  hi = S;
  while (lo < hi) { int mid = (lo + hi) >> 1; if (srow[mid] < g + 1) lo = mid + 1; else hi = mid; }
  const int end = lo;
  float4 acc = make_float4(0.f, 0.f, 0.f, 0.f);
  const float4* p = emb + (size_t)(b * S + start) * D4 + d4;
  for (int s = start; s < end; ++s) {
    float4 e = *p; p += D4;
    acc.x += e.x; acc.y += e.y; acc.z += e.z; acc.w += e.w;
  }
  if (g == 0) out[(size_t)b * D4 + d4] = acc;
  else out[(size_t)B * D4 + ((size_t)b * (S - 1) + (g - 1)) * D4 + d4] = acc;
}

extern "C" void kernel_launch(void* const* d_in, const int* in_sizes, int n_in,
                              void* d_out, int out_size, void* d_ws, size_t ws_size,
                              hipStream_t stream) {
  const float4* emb = (const float4*)d_in[0];
  const int*    seg = (const int*)d_in[1];
  float4*       out = (float4*)d_out;

  const int total  = B * S * D4;             // 6,291,456 threads
  const int blocks = total / BLOCK;          // 24,576 blocks

  const size_t bnd_bytes = (size_t)B * (S + 1) * sizeof(int);  // 131,328 B
  if (ws_size >= bnd_bytes) {
    int* bnd = (int*)d_ws;
    boundaries_kernel<<<B, 256, 0, stream>>>(seg, bnd);
    segsum_kernel2<<<blocks, BLOCK, 0, stream>>>(emb, bnd, out);
  } else {
    segsum_kernel1<<<blocks, BLOCK, 0, stream>>>(emb, seg, out);
  }
}

// Round 3
// 176.755 us; speedup vs baseline: 1.0473x; 1.0033x over previous
//
#include <hip/hip_runtime.h>

// Per-batch segment_sum with SORTED segment ids.
//   embeddings: (B=64, S=512, D=768) fp32; segment_ids: (B,S) int32 sorted.
//   out = concat(agg[:,0] (B,D), agg[:,1:] (B,S-1,D)) — flat B*S*D floats.
//
// R2 post-mortem: two-pass removed the per-thread binary search but kept a
// serialized boundary-load -> emb-load dependent chain + an extra dispatch;
// combined ~58 us vs ~30 us traffic floor.
// R3: single kernel, ONE WAVE PER OUTPUT ROW (b,g). Sorted ids =>
//   start = #(seg[b] < g), end = #(seg[b] <= g).
// The wave loads the whole 2 KB id row with 2 coalesced int4 loads (L1-hot:
// 512 waves/b reuse it) and counts via 16 independent cmp+ballot+popcount —
// no dependent search chain, no boundary array, no second dispatch. Then it
// streams the run (3 float4/lane) and writes 3 coalesced float4.

constexpr int B  = 64;
constexpr int S  = 512;
constexpr int D  = 768;
constexpr int D4 = D / 4;          // 192 float4 per row = 64 lanes x 3
constexpr int BLOCK = 256;         // 4 waves per block

__global__ __launch_bounds__(BLOCK) void segsum_wave_kernel(
    const float4* __restrict__ emb,   // (B*S*D4)
    const int*    __restrict__ seg,   // (B*S)
    float4*       __restrict__ out) { // report (B*D4) then word (B*(S-1)*D4)
  const int wave = (blockIdx.x * BLOCK + threadIdx.x) >> 6;  // [0, B*S)
  const int lane = threadIdx.x & 63;
  const int b    = wave >> 9;        // wave / S
  const int g    = wave & (S - 1);   // wave % S

  // Whole id row in 2 coalesced int4 loads (values only feed counts; order
  // within the row is irrelevant).
  const int4* row = (const int4*)(seg + b * S);  // 128 int4
  const int4 a0 = row[lane];
  const int4 a1 = row[lane + 64];

  // start = #(x < g), end = #(x <= g). 16 independent cmp/ballot/popcount.
  int start = 0, end = 0;
  start += __popcll(__ballot(a0.x < g));
  start += __popcll(__ballot(a0.y < g));
  start += __popcll(__ballot(a0.z < g));
  start += __popcll(__ballot(a0.w < g));
  start += __popcll(__ballot(a1.x < g));
  start += __popcll(__ballot(a1.y < g));
  start += __popcll(__ballot(a1.z < g));
  start += __popcll(__ballot(a1.w < g));
  end   += __popcll(__ballot(a0.x <= g));
  end   += __popcll(__ballot(a0.y <= g));
  end   += __popcll(__ballot(a0.z <= g));
  end   += __popcll(__ballot(a0.w <= g));
  end   += __popcll(__ballot(a1.x <= g));
  end   += __popcll(__ballot(a1.y <= g));
  end   += __popcll(__ballot(a1.z <= g));
  end   += __popcll(__ballot(a1.w <= g));

  // Stream the run: lane i owns float4 columns {i, i+64, i+128}.
  float4 acc0 = make_float4(0.f, 0.f, 0.f, 0.f);
  float4 acc1 = acc0, acc2 = acc0;
  const float4* p = emb + (size_t)(b * S + start) * D4 + lane;
  for (int s = start; s < end; ++s) {          // wave-uniform trip count
    float4 e0 = p[0], e1 = p[64], e2 = p[128];
    acc0.x += e0.x; acc0.y += e0.y; acc0.z += e0.z; acc0.w += e0.w;
    acc1.x += e1.x; acc1.y += e1.y; acc1.z += e1.z; acc1.w += e1.w;
    acc2.x += e2.x; acc2.y += e2.y; acc2.z += e2.z; acc2.w += e2.w;
    p += D4;
  }

  float4* dst = (g == 0)
      ? out + (size_t)b * D4                                        // report_feat
      : out + (size_t)B * D4 + ((size_t)b * (S - 1) + (g - 1)) * D4; // word_feat
  dst[lane]       = acc0;
  dst[lane + 64]  = acc1;
  dst[lane + 128] = acc2;
}

extern "C" void kernel_launch(void* const* d_in, const int* in_sizes, int n_in,
                              void* d_out, int out_size, void* d_ws, size_t ws_size,
                              hipStream_t stream) {
  const float4* emb = (const float4*)d_in[0];
  const int*    seg = (const int*)d_in[1];
  float4*       out = (float4*)d_out;

  const int waves  = B * S;                    // 32768 output rows
  const int blocks = waves / (BLOCK / 64);     // 8192 blocks
  segsum_wave_kernel<<<blocks, BLOCK, 0, stream>>>(emb, seg, out);
}